// Round 1
// baseline (525.414 us; speedup 1.0000x reference)
//
#include <hip/hip_runtime.h>
#include <math.h>

#define TILE 128
#define DDIM 64
#define NTH 256

// ---------------------------------------------------------------------------
// Kernel 1: column means of x1 (the "adjustment"). 64 blocks, one per dim.
// ---------------------------------------------------------------------------
__global__ void col_mean_kernel(const float* __restrict__ x1,
                                float* __restrict__ meanp, int N) {
  const int d = blockIdx.x;              // 0..63
  float s = 0.f;
  for (int i = threadIdx.x; i < N; i += NTH) {
    s += x1[(size_t)i * DDIM + d];
  }
  // wave-64 shuffle reduce
  for (int off = 32; off > 0; off >>= 1) s += __shfl_down(s, off);
  __shared__ float part[NTH / 64];
  if ((threadIdx.x & 63) == 0) part[threadIdx.x >> 6] = s;
  __syncthreads();
  if (threadIdx.x == 0) {
    float t = 0.f;
    #pragma unroll
    for (int w = 0; w < NTH / 64; ++w) t += part[w];
    meanp[d] = t / (float)N;
  }
}

// ---------------------------------------------------------------------------
// Kernel 2: tiled L1-distance + exp.
// 128x128 output tile per block, 256 threads, 8x8 outputs per thread.
// LDS: two 128x64 fp32 tiles (64 KB), float4-granular XOR swizzle so
//   a-reads are conflict-free and b-reads 2-way (free).
// Element (row, 4*g..4*g+3) lives at lds[row*64 + ((g ^ (row&15))<<2)].
// Thread (ty=tid>>4, tx=tid&15) owns rows {16r+ty} and cols {16c+tx};
// since (16r+ty)&15 == ty, the swizzle key is a per-thread constant.
// ---------------------------------------------------------------------------
__global__ __launch_bounds__(NTH, 2) void laplace_tile_kernel(
    const float* __restrict__ x1, const float* __restrict__ x2,
    const float* __restrict__ lsp, const float* __restrict__ meanp,
    float* __restrict__ out, int N, int M) {
  __shared__ float at[TILE * DDIM];
  __shared__ float bt[TILE * DDIM];

  const int tid = threadIdx.x;
  const int ty = tid >> 4;   // 0..15
  const int tx = tid & 15;   // 0..15
  const int row0 = blockIdx.y * TILE;
  const int col0 = blockIdx.x * TILE;
  const float ls = lsp[0];   // THETA(=1) * lengthscale[0]

  // ---- stage both tiles: (x - mean)/ls, swizzled into LDS ----
  {
    const int g = tid & 15;        // float4 group within a row
    const int rb = tid >> 4;       // row within 16-row stripe
    const float4 vm = *(const float4*)&meanp[g * 4];
    #pragma unroll
    for (int it = 0; it < 8; ++it) {
      const int r = it * 16 + rb;
      float4 va = *(const float4*)&x1[(size_t)(row0 + r) * DDIM + g * 4];
      float4 vb = *(const float4*)&x2[(size_t)(col0 + r) * DDIM + g * 4];
      va.x = (va.x - vm.x) / ls;  va.y = (va.y - vm.y) / ls;
      va.z = (va.z - vm.z) / ls;  va.w = (va.w - vm.w) / ls;
      vb.x = (vb.x - vm.x) / ls;  vb.y = (vb.y - vm.y) / ls;
      vb.z = (vb.z - vm.z) / ls;  vb.w = (vb.w - vm.w) / ls;
      const int swz = ((g ^ (r & 15)) << 2);
      *(float4*)&at[r * DDIM + swz] = va;
      *(float4*)&bt[r * DDIM + swz] = vb;
    }
  }
  __syncthreads();

  // ---- compute 8x8 per-thread accumulation over D=64 (16 float4 groups) ----
  float acc[8][8];
  #pragma unroll
  for (int r = 0; r < 8; ++r)
    #pragma unroll
    for (int c = 0; c < 8; ++c) acc[r][c] = 0.f;

  for (int gg = 0; gg < 16; ++gg) {
    const int sa = ((gg ^ ty) << 2);  // swizzled float4 offset for a-rows
    const int sb = ((gg ^ tx) << 2);  // swizzled float4 offset for b-rows
    float4 a[8], b[8];
    #pragma unroll
    for (int r = 0; r < 8; ++r)
      a[r] = *(const float4*)&at[(16 * r + ty) * DDIM + sa];
    #pragma unroll
    for (int c = 0; c < 8; ++c)
      b[c] = *(const float4*)&bt[(16 * c + tx) * DDIM + sb];
    #pragma unroll
    for (int r = 0; r < 8; ++r) {
      #pragma unroll
      for (int c = 0; c < 8; ++c) {
        acc[r][c] += fabsf(a[r].x - b[c].x);
        acc[r][c] += fabsf(a[r].y - b[c].y);
        acc[r][c] += fabsf(a[r].z - b[c].z);
        acc[r][c] += fabsf(a[r].w - b[c].w);
      }
    }
  }

  // ---- epilogue: clamp, exp, store ----
  const float CLAMP = 1e-15f;
  #pragma unroll
  for (int r = 0; r < 8; ++r) {
    const size_t orow = (size_t)(row0 + 16 * r + ty) * (size_t)M + col0 + tx;
    #pragma unroll
    for (int c = 0; c < 8; ++c) {
      out[orow + 16 * c] = expf(-fmaxf(acc[r][c], CLAMP));
    }
  }
}

// ---------------------------------------------------------------------------
extern "C" void kernel_launch(void* const* d_in, const int* in_sizes, int n_in,
                              void* d_out, int out_size, void* d_ws, size_t ws_size,
                              hipStream_t stream) {
  const float* x1 = (const float*)d_in[0];
  const float* x2 = (const float*)d_in[1];
  const float* ls = (const float*)d_in[2];
  float* out = (float*)d_out;
  float* meanp = (float*)d_ws;  // 64 floats

  const int N = in_sizes[0] / DDIM;
  const int M = in_sizes[1] / DDIM;

  col_mean_kernel<<<DDIM, NTH, 0, stream>>>(x1, meanp, N);

  dim3 grid(M / TILE, N / TILE);
  laplace_tile_kernel<<<grid, NTH, 0, stream>>>(x1, x2, ls, meanp, out, N, M);
}

// Round 2
// 523.827 us; speedup vs baseline: 1.0030x; 1.0030x over previous
//
#include <hip/hip_runtime.h>
#include <math.h>

#define DDIM 64
#define TILE 128
#define NTH 256
#define MEAN_BLOCKS 64

// ---------------------------------------------------------------------------
// Mean stage A: 64 blocks, each sums a 128-row slab with fully coalesced
// loads (each wave reads one whole 256B row per iteration).
// partial[b*64 + d] = sum over slab b of column d.
// ---------------------------------------------------------------------------
__global__ void mean_partial_kernel(const float* __restrict__ x1,
                                    float* __restrict__ partial, int N) {
  const int rows_per_block = N / MEAN_BLOCKS;      // 128
  const int r0 = blockIdx.x * rows_per_block;
  const int t = threadIdx.x;
  const int d = t & 63;
  const int rsub = t >> 6;                          // 0..3
  float s = 0.f;
  for (int it = 0; it < rows_per_block; it += 4) {
    s += x1[(size_t)(r0 + it + rsub) * DDIM + d];
  }
  __shared__ float part[4][DDIM];
  part[rsub][d] = s;
  __syncthreads();
  if (t < DDIM) {
    partial[blockIdx.x * DDIM + t] =
        part[0][t] + part[1][t] + part[2][t] + part[3][t];
  }
}

// ---------------------------------------------------------------------------
// Mean stage B: one block folds the 64 partials and divides by N.
// ---------------------------------------------------------------------------
__global__ void mean_final_kernel(const float* __restrict__ partial,
                                  float* __restrict__ meanp, int N) {
  const int t = threadIdx.x;
  const int d = t & 63;
  const int chunk = t >> 6;                         // 0..3
  float s = 0.f;
  for (int b = chunk * (MEAN_BLOCKS / 4); b < (chunk + 1) * (MEAN_BLOCKS / 4); ++b) {
    s += partial[(size_t)b * DDIM + d];
  }
  __shared__ float part[4][DDIM];
  part[chunk][d] = s;
  __syncthreads();
  if (t < DDIM) {
    meanp[t] = (part[0][t] + part[1][t] + part[2][t] + part[3][t]) / (float)N;
  }
}

// ---------------------------------------------------------------------------
// Tiled L1-distance + exp. 128x128 tile, 256 threads, 8x8 per thread.
// LDS: two 128x64 fp32 tiles, float4-granular XOR swizzle:
//   element (row, group g) stored at group position g ^ (row & 15).
// Iterating by a-side POSITION gp: a-read offset = rowbase + gp (immediate),
// logical group = gp ^ ty, so b-read position = gp ^ (ty^tx) — one XOR with a
// per-thread constant. a-reads: 16-lane broadcast x 4 rows (conflict-free);
// b-reads: same spread as round 1 (0 conflicts measured).
// ---------------------------------------------------------------------------
__global__ __launch_bounds__(NTH, 2) void laplace_tile_kernel(
    const float* __restrict__ x1, const float* __restrict__ x2,
    const float* __restrict__ lsp, const float* __restrict__ meanp,
    float* __restrict__ out, int N, int M) {
  __shared__ float at[TILE * DDIM];
  __shared__ float bt[TILE * DDIM];

  const int tid = threadIdx.x;
  const int ty = tid >> 4;                          // 0..15
  const int tx = tid & 15;                          // 0..15
  const int row0 = blockIdx.y * TILE;
  const int col0 = blockIdx.x * TILE;
  const float rls = 1.0f / lsp[0];                  // one real div per thread

  // ---- stage both tiles: (x - mean) * (1/ls), swizzled ----
  {
    const int g = tid & 15;                         // float4 group in row
    const int rb = tid >> 4;                        // row in 16-row stripe
    const float4 vm = *(const float4*)&meanp[g * 4];
    #pragma unroll
    for (int it = 0; it < 8; ++it) {
      const int r = it * 16 + rb;
      float4 va = *(const float4*)&x1[(size_t)(row0 + r) * DDIM + g * 4];
      float4 vb = *(const float4*)&x2[(size_t)(col0 + r) * DDIM + g * 4];
      va.x = (va.x - vm.x) * rls;  va.y = (va.y - vm.y) * rls;
      va.z = (va.z - vm.z) * rls;  va.w = (va.w - vm.w) * rls;
      vb.x = (vb.x - vm.x) * rls;  vb.y = (vb.y - vm.y) * rls;
      vb.z = (vb.z - vm.z) * rls;  vb.w = (vb.w - vm.w) * rls;
      const int swz = ((g ^ (r & 15)) << 2);
      *(float4*)&at[r * DDIM + swz] = va;
      *(float4*)&bt[r * DDIM + swz] = vb;
    }
  }
  __syncthreads();

  const float4* at4 = (const float4*)at;
  const float4* bt4 = (const float4*)bt;
  int aoff[8], boff[8];
  #pragma unroll
  for (int r = 0; r < 8; ++r) aoff[r] = (16 * r + ty) * 16;
  #pragma unroll
  for (int c = 0; c < 8; ++c) boff[c] = (16 * c + tx) * 16;
  const int kx = ty ^ tx;

  float acc[8][8];
  #pragma unroll
  for (int r = 0; r < 8; ++r)
    #pragma unroll
    for (int c = 0; c < 8; ++c) acc[r][c] = 0.f;

  for (int gp = 0; gp < 16; ++gp) {
    const int pb = gp ^ kx;
    float4 b[8];
    #pragma unroll
    for (int c = 0; c < 8; ++c) b[c] = bt4[boff[c] + pb];
    #pragma unroll
    for (int r = 0; r < 8; ++r) {
      const float4 a = at4[aoff[r] + gp];           // immediate offset
      #pragma unroll
      for (int c = 0; c < 8; ++c) {
        // abs folds into VOP3 input modifiers; tree keeps acc chain short
        const float s01 = fabsf(a.x - b[c].x) + fabsf(a.y - b[c].y);
        const float s23 = fabsf(a.z - b[c].z) + fabsf(a.w - b[c].w);
        acc[r][c] += s01 + s23;
      }
    }
  }

  // ---- epilogue: clamp, fast exp, store ----
  #pragma unroll
  for (int r = 0; r < 8; ++r) {
    const size_t orow = (size_t)(row0 + 16 * r + ty) * (size_t)M + col0 + tx;
    #pragma unroll
    for (int c = 0; c < 8; ++c) {
      out[orow + 16 * c] = __expf(-fmaxf(acc[r][c], 1e-15f));
    }
  }
}

// ---------------------------------------------------------------------------
extern "C" void kernel_launch(void* const* d_in, const int* in_sizes, int n_in,
                              void* d_out, int out_size, void* d_ws, size_t ws_size,
                              hipStream_t stream) {
  const float* x1 = (const float*)d_in[0];
  const float* x2 = (const float*)d_in[1];
  const float* ls = (const float*)d_in[2];
  float* out = (float*)d_out;
  float* meanp = (float*)d_ws;                      // 64 floats
  float* partial = meanp + DDIM;                    // 64*64 floats

  const int N = in_sizes[0] / DDIM;
  const int M = in_sizes[1] / DDIM;

  mean_partial_kernel<<<MEAN_BLOCKS, NTH, 0, stream>>>(x1, partial, N);
  mean_final_kernel<<<1, NTH, 0, stream>>>(partial, meanp, N);

  dim3 grid(M / TILE, N / TILE);
  laplace_tile_kernel<<<grid, NTH, 0, stream>>>(x1, x2, ls, meanp, out, N, M);
}